// Round 6
// baseline (1631.257 us; speedup 1.0000x reference)
//
#include <hip/hip_runtime.h>
#include <stdint.h>

// Viterbi CRF decode, batch element 63 only (reference returns scores[-1], paths[-1]).
// feats: [64,1024,512] f32, transitions: [512,512] f32, lengths: [64] int.
// out: [0]=score (f32), [1..1024]=path as f32 (-1 for t>=len).
//
// Protocol (R2 base + pipelined poll): 256 waves, 2 destination rows each.
// fv exchanged via an 8-deep ring of 512 packed (tag<<32 | f32) words,
// relaxed agent-scope atomics only. No barriers, no read-gate (induction:
// a complete tag-t slot implies every producer finished step t-1, hence all
// reads of tag-(t-7) words completed -> depth-8 ring overwrite safe).
//
// R5 falsified per-line reader contention (8x replication = null). This round
// attacks poll SAMPLING quantization: two alternating 8-load batches in
// flight (check A while B flies) halve the sampling gap, and the per-word
// add+lex-argmax update runs at merge time (order-independent lexicographic
// compare == first-index argmax), hiding compute inside the poll gap.
// Candidates are lane-local (j = l+64m, trans rows 2w,2w+1 in registers) —
// no shuffle redistribution. __launch_bounds__(64,1) prevents R4's spill.

#define KK 512
#define TMAX 1024
#define STARTT 510
#define STOPT 511
#define NEGINF (-10000.0f)
#define DSLOT 8

// ws layout
#define WS_BP 0                      // uint16 bp[1024][512]  (1 MB)
#define WS_E 1048576                 // uint16 E[64][512]     (64 KB)
#define WS_BEST 1114112              // int best (padded to 64 B)
#define WS_FV 1114176                // uint64 fv[8][512]     (32 KB)

__device__ __forceinline__ int read_len(const void* lp) {
  // lengths may be int32 or int64; int64 little-endian has hi-word 0 at odd int32 slots
  const int* q = (const int*)lp;
  return (q[1] == 0) ? (int)(((const long long*)lp)[63]) : q[63];
}

__global__ void k_init(char* ws) {
  uint64_t* fvb = (uint64_t*)(ws + WS_FV);
  const int tid = threadIdx.x;  // 512
  const float v0 = (tid == STARTT) ? 0.0f : NEGINF;
  fvb[tid] = (uint64_t)__float_as_uint(v0);  // tag 0 in hi32
#pragma unroll
  for (int b = 1; b < DSLOT; ++b) fvb[b * KK + tid] = 0x7FFFFFFF00000000ull;
}

#define MERGE_BATCH(arr)                                                       \
  _Pragma("unroll") for (int m = 0; m < 8; ++m) {                              \
    if ((stale & (1u << m)) && (int)(uint32_t)(arr[m] >> 32) == t) {           \
      stale &= ~(1u << m);                                                     \
      const float val = __uint_as_float((uint32_t)arr[m]);                     \
      const int j = l + 64 * m;                                                \
      const float c0 = val + tr0[m];                                           \
      if (c0 > bv0 || (c0 == bv0 && j < bj0)) { bv0 = c0; bj0 = j; }           \
      const float c1 = val + tr1[m];                                           \
      if (c1 > bv1 || (c1 == bv1 && j < bj1)) { bv1 = c1; bj1 = j; }           \
    }                                                                          \
  }

__global__ void __launch_bounds__(64, 1) k_forward(
    const float* __restrict__ feats, const float* __restrict__ trans,
    const void* __restrict__ lens, float* __restrict__ out, char* ws) {
  const int len = read_len(lens);
  const int w = blockIdx.x;   // 0..255, one wave per WG
  const int l = threadIdx.x;  // 0..63
  const int R0 = 2 * w;       // my rows: R0, R0+1
  uint64_t* fvb = (uint64_t*)(ws + WS_FV);
  uint16_t* bp = (uint16_t*)(ws + WS_BP);

  // transitions rows R0,R0+1 at cols l+64m — lane-local candidates
  float tr0[8], tr1[8];
#pragma unroll
  for (int m = 0; m < 8; ++m) {
    tr0[m] = trans[(size_t)R0 * KK + l + 64 * m];
    tr1[m] = trans[(size_t)(R0 + 1) * KK + l + 64 * m];
  }

  const float* fb = feats + 63ll * TMAX * KK;  // batch 63
  float featNext = (l < 2) ? fb[R0 + l] : 0.0f;

  for (int t = 0; t < len; ++t) {
    uint64_t* slot = fvb + (size_t)(t & (DSLOT - 1)) * KK;
    float bv0 = -3.0e38f, bv1 = -3.0e38f;
    int bj0 = 0x7fffffff, bj1 = 0x7fffffff;
    uint32_t stale = 0xFFu;
    uint64_t a[8], b[8];
    // prologue: batch A in flight
#pragma unroll
    for (int m = 0; m < 8; ++m)
      a[m] = __hip_atomic_load(&slot[l + 64 * m], __ATOMIC_RELAXED, __HIP_MEMORY_SCOPE_AGENT);
    while (true) {
      // issue B, then consume A (A done, B still flying -> sampling gap ~RTT/2)
#pragma unroll
      for (int m = 0; m < 8; ++m)
        b[m] = __hip_atomic_load(&slot[l + 64 * m], __ATOMIC_RELAXED, __HIP_MEMORY_SCOPE_AGENT);
      MERGE_BATCH(a)
      if (!__any(stale != 0)) break;
#pragma unroll
      for (int m = 0; m < 8; ++m)
        a[m] = __hip_atomic_load(&slot[l + 64 * m], __ATOMIC_RELAXED, __HIP_MEMORY_SCOPE_AGENT);
      MERGE_BATCH(b)
      if (!__any(stale != 0)) break;
    }

    const float featCur = featNext;
    if (l < 2 && t + 1 < len) featNext = fb[(size_t)(t + 1) * KK + R0 + l];

    // dual interleaved cross-lane lex-reduce (first-index tie-break)
#pragma unroll
    for (int m = 32; m >= 1; m >>= 1) {
      const float ov0 = __shfl_xor(bv0, m);
      const int oj0 = __shfl_xor(bj0, m);
      const float ov1 = __shfl_xor(bv1, m);
      const int oj1 = __shfl_xor(bj1, m);
      if (ov0 > bv0 || (ov0 == bv0 && oj0 < bj0)) { bv0 = ov0; bj0 = oj0; }
      if (ov1 > bv1 || (ov1 == bv1 && oj1 < bj1)) { bv1 = ov1; bj1 = oj1; }
    }
    // lanes 0,1 publish rows R0,R0+1: adjacent 8B words -> one transaction
    if (l < 2) {
      const float bv = l ? bv1 : bv0;
      const int bj = l ? bj1 : bj0;
      const float vit = bv + featCur;
      const uint64_t pk = ((uint64_t)(uint32_t)(t + 1) << 32) | (uint64_t)__float_as_uint(vit);
      __hip_atomic_store(&fvb[(size_t)((t + 1) & (DSLOT - 1)) * KK + R0 + l], pk,
                         __ATOMIC_RELAXED, __HIP_MEMORY_SCOPE_AGENT);
      bp[(size_t)t * KK + R0 + l] = (uint16_t)bj;  // after fv store: off critical path
    }
  }

  if (w != 0) return;
  // terminal: score = max_j fv[j] + trans[STOP][j], best = first argmax
  {
    uint64_t* slot = fvb + (size_t)(len & (DSLOT - 1)) * KK;
    uint64_t v[8];
    bool ok;
    do {
#pragma unroll
      for (int m = 0; m < 8; ++m)
        v[m] = __hip_atomic_load(&slot[l + 64 * m], __ATOMIC_RELAXED, __HIP_MEMORY_SCOPE_AGENT);
      ok = true;
#pragma unroll
      for (int m = 0; m < 8; ++m) ok = ok && ((int)(uint32_t)(v[m] >> 32) == len);
    } while (__any(!ok));
    float tv;
    int tj;
#pragma unroll
    for (int m = 0; m < 8; ++m) {
      float x = __uint_as_float((uint32_t)v[m]) + trans[(size_t)STOPT * KK + l + 64 * m];
      if (m == 0) {
        tv = x; tj = l;
      } else if (x > tv) {
        tv = x; tj = l + 64 * m;
      }
    }
#pragma unroll
    for (int m = 32; m >= 1; m >>= 1) {
      float ov = __shfl_xor(tv, m);
      int oj = __shfl_xor(tj, m);
      if (ov > tv || (ov == tv && oj < tj)) { tv = ov; tj = oj; }
    }
    if (l == 0) {
      out[0] = tv;
      *((int*)(ws + WS_BEST)) = tj;
    }
  }
}

// speculative backtrack: per 16-step segment, walk all 512 possible entry tags
__global__ void __launch_bounds__(512) k_walk(const void* __restrict__ lens, char* ws) {
  const int len = read_len(lens);
  const uint16_t* bp = (const uint16_t*)(ws + WS_BP);
  uint16_t* E = (uint16_t*)(ws + WS_E);
  const int s = blockIdx.x;   // 64 segments
  const int k = threadIdx.x;  // 512 entry tags
  int tag = k;
  const int lo = s * 16;
  for (int t = lo + 15; t >= lo; --t)
    if (t < len) tag = bp[(size_t)t * KK + tag];
  E[s * KK + k] = (uint16_t)tag;
}

// compose segment maps from the top, then re-walk each segment and emit the path
__global__ void __launch_bounds__(64) k_emit(
    const void* __restrict__ lens, float* __restrict__ out, char* ws) {
  const int len = read_len(lens);
  const uint16_t* bp = (const uint16_t*)(ws + WS_BP);
  const uint16_t* E = (const uint16_t*)(ws + WS_E);
  __shared__ int entry[64];
  const int tid = threadIdx.x;
  if (tid == 0) {
    int st = *((const int*)(ws + WS_BEST));
    for (int s = 63; s >= 0; --s) { entry[s] = st; st = E[s * KK + st]; }
  }
  __syncthreads();
  {
    const int s = tid;
    int st = entry[s];
    for (int t = s * 16 + 15; t >= s * 16; --t) {
      if (t < len) {
        out[1 + t] = (float)st;
        st = bp[(size_t)t * KK + st];
      } else {
        out[1 + t] = -1.0f;
      }
    }
  }
}

extern "C" void kernel_launch(void* const* d_in, const int* in_sizes, int n_in,
                              void* d_out, int out_size, void* d_ws, size_t ws_size,
                              hipStream_t stream) {
  const float* feats = (const float*)d_in[0];
  const float* trans = (const float*)d_in[1];
  const void* lens = d_in[2];
  float* out = (float*)d_out;
  char* ws = (char*)d_ws;
  (void)in_sizes; (void)n_in; (void)out_size; (void)ws_size;

  k_init<<<1, 512, 0, stream>>>(ws);
  k_forward<<<256, 64, 0, stream>>>(feats, trans, lens, out, ws);
  k_walk<<<64, 512, 0, stream>>>(lens, ws);
  k_emit<<<1, 64, 0, stream>>>(lens, out, ws);
}

// Round 7
// 1482.204 us; speedup vs baseline: 1.1006x; 1.1006x over previous
//
#include <hip/hip_runtime.h>
#include <stdint.h>

// Viterbi CRF decode, batch element 63 only (reference returns scores[-1], paths[-1]).
// feats: [64,1024,512] f32, transitions: [512,512] f32, lengths: [64] int.
// out: [0]=score (f32), [1..1024]=path as f32 (-1 for t>=len).
//
// Protocol: 256 waves, 2 destination rows each. fv exchanged via an 8-deep
// ring of 512 packed (tag<<32 | f32) words, relaxed agent-scope atomics only.
// No barriers, no read-gate (induction: complete tag-t slot implies all
// producers finished step t-1, so all tag-(t-7) reads are done -> depth-8
// ring overwrite safe).
//
// Experiment history baked into this design:
//   R3 (512 waves)        -> 2.3x WORSE: duration scales with total poll
//   R6 (2-deep cont. poll)-> 2.6x WORSE:   request pressure (queue inflation)
//   R5 (8x replication)   -> null: NOT per-line reader contention
//   R4 (4 rows/wave)      -> spilled (VGPR>48): keep footprint lean
// => poll must stay SELF-THROTTLED (issue 8, wait-all, check). This round's
// single change vs R2: candidate add + lex-argmax folded into the merge pass
// (lane-local j = l+64m vs trans rows 2w,2w+1 in regs — no shuffle
// redistribution, no post-detect serial chain; only the 6-level reduce
// remains after detection).

#define KK 512
#define TMAX 1024
#define STARTT 510
#define STOPT 511
#define NEGINF (-10000.0f)
#define DSLOT 8

// ws layout
#define WS_BP 0                      // uint16 bp[1024][512]  (1 MB)
#define WS_E 1048576                 // uint16 E[64][512]     (64 KB)
#define WS_BEST 1114112              // int best (padded to 64 B)
#define WS_FV 1114176                // uint64 fv[8][512]     (32 KB)

__device__ __forceinline__ int read_len(const void* lp) {
  // lengths may be int32 or int64; int64 little-endian has hi-word 0 at odd int32 slots
  const int* q = (const int*)lp;
  return (q[1] == 0) ? (int)(((const long long*)lp)[63]) : q[63];
}

__global__ void k_init(char* ws) {
  uint64_t* fvb = (uint64_t*)(ws + WS_FV);
  const int tid = threadIdx.x;  // 512
  const float v0 = (tid == STARTT) ? 0.0f : NEGINF;
  fvb[tid] = (uint64_t)__float_as_uint(v0);  // tag 0 in hi32
#pragma unroll
  for (int b = 1; b < DSLOT; ++b) fvb[b * KK + tid] = 0x7FFFFFFF00000000ull;
}

__global__ void __launch_bounds__(64, 1) k_forward(
    const float* __restrict__ feats, const float* __restrict__ trans,
    const void* __restrict__ lens, float* __restrict__ out, char* ws) {
  const int len = read_len(lens);
  const int w = blockIdx.x;   // 0..255, one wave per WG
  const int l = threadIdx.x;  // 0..63
  const int R0 = 2 * w;       // my rows: R0, R0+1
  uint64_t* fvb = (uint64_t*)(ws + WS_FV);
  uint16_t* bp = (uint16_t*)(ws + WS_BP);

  // transitions rows R0,R0+1 at cols l+64m — lane-local candidates
  float tr0[8], tr1[8];
#pragma unroll
  for (int m = 0; m < 8; ++m) {
    tr0[m] = trans[(size_t)R0 * KK + l + 64 * m];
    tr1[m] = trans[(size_t)(R0 + 1) * KK + l + 64 * m];
  }

  const float* fb = feats + 63ll * TMAX * KK;  // batch 63
  float featNext = (l < 2) ? fb[R0 + l] : 0.0f;

  for (int t = 0; t < len; ++t) {
    uint64_t* slot = fvb + (size_t)(t & (DSLOT - 1)) * KK;
    float bv0 = -3.0e38f, bv1 = -3.0e38f;
    int bj0 = 0x7fffffff, bj1 = 0x7fffffff;
    uint32_t stale = 0xFFu;
    // self-throttled poll (R2 discipline): issue 8, wait-all, merge fresh words
    do {
      uint64_t v[8];
#pragma unroll
      for (int m = 0; m < 8; ++m)
        v[m] = __hip_atomic_load(&slot[l + 64 * m], __ATOMIC_RELAXED, __HIP_MEMORY_SCOPE_AGENT);
#pragma unroll
      for (int m = 0; m < 8; ++m) {
        if ((stale & (1u << m)) && (int)(uint32_t)(v[m] >> 32) == t) {
          stale &= ~(1u << m);
          const float val = __uint_as_float((uint32_t)v[m]);
          const int j = l + 64 * m;
          const float c0 = val + tr0[m];
          if (c0 > bv0 || (c0 == bv0 && j < bj0)) { bv0 = c0; bj0 = j; }
          const float c1 = val + tr1[m];
          if (c1 > bv1 || (c1 == bv1 && j < bj1)) { bv1 = c1; bj1 = j; }
        }
      }
    } while (__any(stale != 0));

    const float featCur = featNext;
    if (l < 2 && t + 1 < len) featNext = fb[(size_t)(t + 1) * KK + R0 + l];

    // dual interleaved cross-lane lex-reduce (first-index tie-break)
#pragma unroll
    for (int m = 32; m >= 1; m >>= 1) {
      const float ov0 = __shfl_xor(bv0, m);
      const int oj0 = __shfl_xor(bj0, m);
      const float ov1 = __shfl_xor(bv1, m);
      const int oj1 = __shfl_xor(bj1, m);
      if (ov0 > bv0 || (ov0 == bv0 && oj0 < bj0)) { bv0 = ov0; bj0 = oj0; }
      if (ov1 > bv1 || (ov1 == bv1 && oj1 < bj1)) { bv1 = ov1; bj1 = oj1; }
    }
    // lanes 0,1 publish rows R0,R0+1: adjacent 8B words -> one transaction
    if (l < 2) {
      const float bv = l ? bv1 : bv0;
      const int bj = l ? bj1 : bj0;
      const float vit = bv + featCur;
      const uint64_t pk = ((uint64_t)(uint32_t)(t + 1) << 32) | (uint64_t)__float_as_uint(vit);
      __hip_atomic_store(&fvb[(size_t)((t + 1) & (DSLOT - 1)) * KK + R0 + l], pk,
                         __ATOMIC_RELAXED, __HIP_MEMORY_SCOPE_AGENT);
      bp[(size_t)t * KK + R0 + l] = (uint16_t)bj;  // after fv store: off critical path
    }
  }

  if (w != 0) return;
  // terminal: score = max_j fv[j] + trans[STOP][j], best = first argmax
  {
    uint64_t* slot = fvb + (size_t)(len & (DSLOT - 1)) * KK;
    uint64_t v[8];
    bool ok;
    do {
#pragma unroll
      for (int m = 0; m < 8; ++m)
        v[m] = __hip_atomic_load(&slot[l + 64 * m], __ATOMIC_RELAXED, __HIP_MEMORY_SCOPE_AGENT);
      ok = true;
#pragma unroll
      for (int m = 0; m < 8; ++m) ok = ok && ((int)(uint32_t)(v[m] >> 32) == len);
    } while (__any(!ok));
    float tv;
    int tj;
#pragma unroll
    for (int m = 0; m < 8; ++m) {
      float x = __uint_as_float((uint32_t)v[m]) + trans[(size_t)STOPT * KK + l + 64 * m];
      if (m == 0) {
        tv = x; tj = l;
      } else if (x > tv) {
        tv = x; tj = l + 64 * m;
      }
    }
#pragma unroll
    for (int m = 32; m >= 1; m >>= 1) {
      float ov = __shfl_xor(tv, m);
      int oj = __shfl_xor(tj, m);
      if (ov > tv || (ov == tv && oj < tj)) { tv = ov; tj = oj; }
    }
    if (l == 0) {
      out[0] = tv;
      *((int*)(ws + WS_BEST)) = tj;
    }
  }
}

// speculative backtrack: per 16-step segment, walk all 512 possible entry tags
__global__ void __launch_bounds__(512) k_walk(const void* __restrict__ lens, char* ws) {
  const int len = read_len(lens);
  const uint16_t* bp = (const uint16_t*)(ws + WS_BP);
  uint16_t* E = (uint16_t*)(ws + WS_E);
  const int s = blockIdx.x;   // 64 segments
  const int k = threadIdx.x;  // 512 entry tags
  int tag = k;
  const int lo = s * 16;
  for (int t = lo + 15; t >= lo; --t)
    if (t < len) tag = bp[(size_t)t * KK + tag];
  E[s * KK + k] = (uint16_t)tag;
}

// compose segment maps from the top, then re-walk each segment and emit the path
__global__ void __launch_bounds__(64) k_emit(
    const void* __restrict__ lens, float* __restrict__ out, char* ws) {
  const int len = read_len(lens);
  const uint16_t* bp = (const uint16_t*)(ws + WS_BP);
  const uint16_t* E = (const uint16_t*)(ws + WS_E);
  __shared__ int entry[64];
  const int tid = threadIdx.x;
  if (tid == 0) {
    int st = *((const int*)(ws + WS_BEST));
    for (int s = 63; s >= 0; --s) { entry[s] = st; st = E[s * KK + st]; }
  }
  __syncthreads();
  {
    const int s = tid;
    int st = entry[s];
    for (int t = s * 16 + 15; t >= s * 16; --t) {
      if (t < len) {
        out[1 + t] = (float)st;
        st = bp[(size_t)t * KK + st];
      } else {
        out[1 + t] = -1.0f;
      }
    }
  }
}

extern "C" void kernel_launch(void* const* d_in, const int* in_sizes, int n_in,
                              void* d_out, int out_size, void* d_ws, size_t ws_size,
                              hipStream_t stream) {
  const float* feats = (const float*)d_in[0];
  const float* trans = (const float*)d_in[1];
  const void* lens = d_in[2];
  float* out = (float*)d_out;
  char* ws = (char*)d_ws;
  (void)in_sizes; (void)n_in; (void)out_size; (void)ws_size;

  k_init<<<1, 512, 0, stream>>>(ws);
  k_forward<<<256, 64, 0, stream>>>(feats, trans, lens, out, ws);
  k_walk<<<64, 512, 0, stream>>>(lens, ws);
  k_emit<<<1, 64, 0, stream>>>(lens, out, ws);
}

// Round 8
// 1014.454 us; speedup vs baseline: 1.6080x; 1.4611x over previous
//
#include <hip/hip_runtime.h>
#include <stdint.h>

// Viterbi CRF decode, batch element 63 only (reference returns scores[-1], paths[-1]).
// feats: [64,1024,512] f32, transitions: [512,512] f32, lengths: [64] int.
// out: [0]=score (f32), [1..1024]=path as f32 (-1 for t>=len).
//
// Protocol: fv exchanged via an 8-deep ring of 512 packed (tag<<32 | f32)
// words, relaxed agent-scope atomics only. No barriers, no read-gate
// (induction: a complete tag-t slot implies all producers finished step t-1,
// so all tag-(t-7) reads are done -> depth-8 ring overwrite safe).
//
// Experiment matrix (all absmax=0):
//   R2/R5: 256 waves, BARE tag-poll, compute-after-detect  -> 0.61 us/step
//   R3:    512 waves, same loop                            -> 1.42 (2.3x)
//   R4:    128 waves x4 rows, NO (64,1) bound -> SPILLED   -> 1.25 (confound)
//   R6:    2-deep continuous poll                          -> 1.58
//   R7:    stale-predicated in-merge compute               -> 1.45
// => the bare issue-8/wait-all/tag-check loop is the only shape that sustains
//    0.61; any fattening of the loop body or outstanding depth regresses 2x+.
// This round: R4's wave-count reduction redone CLEANLY — 128 waves x 4 rows,
// R2-verbatim poll loop, lane-local candidates (no redistribution), compute
// strictly after detection, __launch_bounds__(64,1) so ~85 VGPRs fit (no
// spill), named scalars for publish selection (no runtime-indexed arrays).

#define KK 512
#define TMAX 1024
#define STARTT 510
#define STOPT 511
#define NEGINF (-10000.0f)
#define DSLOT 8
#define RPW 4            // rows per wave
#define NWG (KK / RPW)   // 128

// ws layout
#define WS_BP 0                      // uint16 bp[1024][512]  (1 MB)
#define WS_E 1048576                 // uint16 E[64][512]     (64 KB)
#define WS_BEST 1114112              // int best (padded to 64 B)
#define WS_FV 1114176                // uint64 fv[8][512]     (32 KB)

__device__ __forceinline__ int read_len(const void* lp) {
  // lengths may be int32 or int64; int64 little-endian has hi-word 0 at odd int32 slots
  const int* q = (const int*)lp;
  return (q[1] == 0) ? (int)(((const long long*)lp)[63]) : q[63];
}

__global__ void k_init(char* ws) {
  uint64_t* fvb = (uint64_t*)(ws + WS_FV);
  const int tid = threadIdx.x;  // 512
  const float v0 = (tid == STARTT) ? 0.0f : NEGINF;
  fvb[tid] = (uint64_t)__float_as_uint(v0);  // tag 0 in hi32
#pragma unroll
  for (int b = 1; b < DSLOT; ++b) fvb[b * KK + tid] = 0x7FFFFFFF00000000ull;
}

// in-lane tree argmax over 8 candidates c[0..7] at indices j = l + 64m.
// ">=" keeps lower m => lower j => first-index tie-break within the lane.
#define LANE_TREE8(cv, OUTV, OUTJ)                                             \
  {                                                                            \
    float _v4[4]; int _i4[4];                                                  \
    _Pragma("unroll") for (int m = 0; m < 4; ++m) {                            \
      const bool L = cv[2 * m] >= cv[2 * m + 1];                               \
      _v4[m] = L ? cv[2 * m] : cv[2 * m + 1];                                  \
      _i4[m] = L ? 2 * m : 2 * m + 1;                                          \
    }                                                                          \
    float _v2[2]; int _i2[2];                                                  \
    _Pragma("unroll") for (int m = 0; m < 2; ++m) {                            \
      const bool L = _v4[2 * m] >= _v4[2 * m + 1];                             \
      _v2[m] = L ? _v4[2 * m] : _v4[2 * m + 1];                                \
      _i2[m] = L ? _i4[2 * m] : _i4[2 * m + 1];                                \
    }                                                                          \
    const bool L = _v2[0] >= _v2[1];                                           \
    OUTV = L ? _v2[0] : _v2[1];                                                \
    OUTJ = l + 64 * (L ? _i2[0] : _i2[1]);                                     \
  }

__global__ void __launch_bounds__(64, 1) k_forward(
    const float* __restrict__ feats, const float* __restrict__ trans,
    const void* __restrict__ lens, float* __restrict__ out, char* ws) {
  const int len = read_len(lens);
  const int w = blockIdx.x;   // 0..127, one wave per WG
  const int l = threadIdx.x;  // 0..63
  const int R0 = RPW * w;     // my rows: R0..R0+3
  uint64_t* fvb = (uint64_t*)(ws + WS_FV);
  uint16_t* bp = (uint16_t*)(ws + WS_BP);

  // transitions rows R0..R0+3 at cols l+64m — lane-local candidates
  float tr0[8], tr1[8], tr2[8], tr3[8];
#pragma unroll
  for (int m = 0; m < 8; ++m) {
    tr0[m] = trans[(size_t)(R0 + 0) * KK + l + 64 * m];
    tr1[m] = trans[(size_t)(R0 + 1) * KK + l + 64 * m];
    tr2[m] = trans[(size_t)(R0 + 2) * KK + l + 64 * m];
    tr3[m] = trans[(size_t)(R0 + 3) * KK + l + 64 * m];
  }

  const float* fb = feats + 63ll * TMAX * KK;  // batch 63
  float featNext = (l < RPW) ? fb[R0 + l] : 0.0f;

  for (int t = 0; t < len; ++t) {
    uint64_t* slot = fvb + (size_t)(t & (DSLOT - 1)) * KK;
    // --- R2-verbatim bare poll: issue 8, wait-all, tag-check, repeat ---
    uint64_t v[8];
    bool ok;
    do {
#pragma unroll
      for (int m = 0; m < 8; ++m)
        v[m] = __hip_atomic_load(&slot[l + 64 * m], __ATOMIC_RELAXED, __HIP_MEMORY_SCOPE_AGENT);
      ok = true;
#pragma unroll
      for (int m = 0; m < 8; ++m) ok = ok && ((int)(uint32_t)(v[m] >> 32) == t);
    } while (__any(!ok));
    float fvals[8];
#pragma unroll
    for (int m = 0; m < 8; ++m) fvals[m] = __uint_as_float((uint32_t)v[m]);

    const float featCur = featNext;
    if (l < RPW && t + 1 < len) featNext = fb[(size_t)(t + 1) * KK + R0 + l];

    // --- post-detect compute: 4 rows, lane-local, ILP-friendly ---
    float c0[8], c1[8], c2[8], c3[8];
#pragma unroll
    for (int m = 0; m < 8; ++m) {
      c0[m] = fvals[m] + tr0[m];
      c1[m] = fvals[m] + tr1[m];
      c2[m] = fvals[m] + tr2[m];
      c3[m] = fvals[m] + tr3[m];
    }
    float bv0, bv1, bv2, bv3;
    int bj0, bj1, bj2, bj3;
    LANE_TREE8(c0, bv0, bj0)
    LANE_TREE8(c1, bv1, bj1)
    LANE_TREE8(c2, bv2, bj2)
    LANE_TREE8(c3, bv3, bj3)
    // 4-way interleaved cross-lane lex-reduce (first-index tie-break)
#pragma unroll
    for (int m = 32; m >= 1; m >>= 1) {
      const float o0 = __shfl_xor(bv0, m); const int p0 = __shfl_xor(bj0, m);
      const float o1 = __shfl_xor(bv1, m); const int p1 = __shfl_xor(bj1, m);
      const float o2 = __shfl_xor(bv2, m); const int p2 = __shfl_xor(bj2, m);
      const float o3 = __shfl_xor(bv3, m); const int p3 = __shfl_xor(bj3, m);
      if (o0 > bv0 || (o0 == bv0 && p0 < bj0)) { bv0 = o0; bj0 = p0; }
      if (o1 > bv1 || (o1 == bv1 && p1 < bj1)) { bv1 = o1; bj1 = p1; }
      if (o2 > bv2 || (o2 == bv2 && p2 < bj2)) { bv2 = o2; bj2 = p2; }
      if (o3 > bv3 || (o3 == bv3 && p3 < bj3)) { bv3 = o3; bj3 = p3; }
    }
    // lanes 0..3 publish rows R0..R0+3: 4 adjacent 8B words -> one 32B txn
    float mybv = bv0; int mybj = bj0;
    if (l == 1) { mybv = bv1; mybj = bj1; }
    if (l == 2) { mybv = bv2; mybj = bj2; }
    if (l == 3) { mybv = bv3; mybj = bj3; }
    if (l < RPW) {
      const float vit = mybv + featCur;
      const uint64_t pk = ((uint64_t)(uint32_t)(t + 1) << 32) | (uint64_t)__float_as_uint(vit);
      __hip_atomic_store(&fvb[(size_t)((t + 1) & (DSLOT - 1)) * KK + R0 + l], pk,
                         __ATOMIC_RELAXED, __HIP_MEMORY_SCOPE_AGENT);
      bp[(size_t)t * KK + R0 + l] = (uint16_t)mybj;  // after fv store: off critical path
    }
  }

  if (w != 0) return;
  // terminal: score = max_j fv[j] + trans[STOP][j], best = first argmax
  {
    uint64_t* slot = fvb + (size_t)(len & (DSLOT - 1)) * KK;
    uint64_t v[8];
    bool ok;
    do {
#pragma unroll
      for (int m = 0; m < 8; ++m)
        v[m] = __hip_atomic_load(&slot[l + 64 * m], __ATOMIC_RELAXED, __HIP_MEMORY_SCOPE_AGENT);
      ok = true;
#pragma unroll
      for (int m = 0; m < 8; ++m) ok = ok && ((int)(uint32_t)(v[m] >> 32) == len);
    } while (__any(!ok));
    float tv;
    int tj;
#pragma unroll
    for (int m = 0; m < 8; ++m) {
      float x = __uint_as_float((uint32_t)v[m]) + trans[(size_t)STOPT * KK + l + 64 * m];
      if (m == 0) {
        tv = x; tj = l;
      } else if (x > tv) {
        tv = x; tj = l + 64 * m;
      }
    }
#pragma unroll
    for (int m = 32; m >= 1; m >>= 1) {
      float ov = __shfl_xor(tv, m);
      int oj = __shfl_xor(tj, m);
      if (ov > tv || (ov == tv && oj < tj)) { tv = ov; tj = oj; }
    }
    if (l == 0) {
      out[0] = tv;
      *((int*)(ws + WS_BEST)) = tj;
    }
  }
}

// speculative backtrack: per 16-step segment, walk all 512 possible entry tags
__global__ void __launch_bounds__(512) k_walk(const void* __restrict__ lens, char* ws) {
  const int len = read_len(lens);
  const uint16_t* bp = (const uint16_t*)(ws + WS_BP);
  uint16_t* E = (uint16_t*)(ws + WS_E);
  const int s = blockIdx.x;   // 64 segments
  const int k = threadIdx.x;  // 512 entry tags
  int tag = k;
  const int lo = s * 16;
  for (int t = lo + 15; t >= lo; --t)
    if (t < len) tag = bp[(size_t)t * KK + tag];
  E[s * KK + k] = (uint16_t)tag;
}

// compose segment maps from the top, then re-walk each segment and emit the path
__global__ void __launch_bounds__(64) k_emit(
    const void* __restrict__ lens, float* __restrict__ out, char* ws) {
  const int len = read_len(lens);
  const uint16_t* bp = (const uint16_t*)(ws + WS_BP);
  const uint16_t* E = (const uint16_t*)(ws + WS_E);
  __shared__ int entry[64];
  const int tid = threadIdx.x;
  if (tid == 0) {
    int st = *((const int*)(ws + WS_BEST));
    for (int s = 63; s >= 0; --s) { entry[s] = st; st = E[s * KK + st]; }
  }
  __syncthreads();
  {
    const int s = tid;
    int st = entry[s];
    for (int t = s * 16 + 15; t >= s * 16; --t) {
      if (t < len) {
        out[1 + t] = (float)st;
        st = bp[(size_t)t * KK + st];
      } else {
        out[1 + t] = -1.0f;
      }
    }
  }
}

extern "C" void kernel_launch(void* const* d_in, const int* in_sizes, int n_in,
                              void* d_out, int out_size, void* d_ws, size_t ws_size,
                              hipStream_t stream) {
  const float* feats = (const float*)d_in[0];
  const float* trans = (const float*)d_in[1];
  const void* lens = d_in[2];
  float* out = (float*)d_out;
  char* ws = (char*)d_ws;
  (void)in_sizes; (void)n_in; (void)out_size; (void)ws_size;

  k_init<<<1, 512, 0, stream>>>(ws);
  k_forward<<<NWG, 64, 0, stream>>>(feats, trans, lens, out, ws);
  k_walk<<<64, 512, 0, stream>>>(lens, ws);
  k_emit<<<1, 64, 0, stream>>>(lens, out, ws);
}

// Round 9
// 647.010 us; speedup vs baseline: 2.5212x; 1.5679x over previous
//
#include <hip/hip_runtime.h>
#include <stdint.h>

// Viterbi CRF decode, batch element 63 only (reference returns scores[-1], paths[-1]).
// feats: [64,1024,512] f32, transitions: [512,512] f32, lengths: [64] int.
// out: [0]=score (f32), [1..1024]=path as f32 (-1 for t>=len).
//
// FINAL FORM — measured-best (R2, 645.8 us total; forward 628 us = 0.61 us/step).
// Protocol: 256 waves (one per WG), 2 destination rows each. fv exchanged via
// an 8-deep ring of 512 packed (tag<<32 | f32) words in ws, relaxed
// agent-scope atomics only (payload rides with the tag in one 8B word — no
// ordering needed). No barriers, no read-gate: a fully-fresh tag-t slot
// implies every producer finished step t-1, hence all reads of the slot being
// overwritten (tag t-7) completed -> depth-8 ring overwrite is safe.
//
// Experiment matrix that selected this shape (all variants absmax=0):
//   R2/R5: 256 waves, BARE issue-8/wait-all/tag-check poll  -> 0.61 us/step
//   R3:    512 waves, same loop                             -> 1.42 (2.3x)
//   R4:    128 waves x4 rows (spilled: VGPR cap + LDS)      -> 1.25
//   R5:    8x fv replication (ncopy=8)                      -> null (not
//          per-line reader contention; store fan-out adds ~0)
//   R6:    2-deep continuously-pipelined poll               -> 1.58 (2.6x)
//   R7:    stale-predicated in-merge compute                -> 1.45 (2.3x)
//   R8:    128 waves x4 rows, (64,1) bound (VGPR squeeze)   -> 0.97
// => any fattening of the poll loop body, outstanding-load depth, or per-wave
//    register footprint breaks the 0.61 cadence. Keep this loop verbatim.
// Floor decomposition (~1470 cy/step): store->LLC visibility ~300 + sampling
// ~225 + load return ~450 + compute/reduce ~250 + straggler jitter.

#define KK 512
#define TMAX 1024
#define STARTT 510
#define STOPT 511
#define NEGINF (-10000.0f)
#define DSLOT 8

// ws layout
#define WS_FV 0                      // uint64 fvbuf[8][512]  (32 KB)
#define WS_BEST 32768                // int best
#define WS_BP 40960                  // uint16 bp[1024][512]  (1 MB)
#define WS_E (40960 + 1048576)       // uint16 E[64][512]     (64 KB)

__device__ __forceinline__ int read_len(const void* lp) {
  // lengths may be int32 or int64; int64 little-endian has hi-word 0 at odd int32 slots
  const int* q = (const int*)lp;
  return (q[1] == 0) ? (int)(((const long long*)lp)[63]) : q[63];
}

__global__ void k_init(char* ws) {
  uint64_t* fvb = (uint64_t*)(ws + WS_FV);
  int tid = threadIdx.x;  // 512
  float v = (tid == STARTT) ? 0.0f : NEGINF;
  fvb[tid] = (uint64_t)__float_as_uint(v);  // tag 0 in hi32
#pragma unroll
  for (int b = 1; b < DSLOT; ++b) fvb[b * KK + tid] = 0x7FFFFFFF00000000ull;
}

__global__ void __launch_bounds__(64) k_forward(
    const float* __restrict__ feats, const float* __restrict__ trans,
    const void* __restrict__ lens, float* __restrict__ out, char* ws) {
  const int len = read_len(lens);
  const int w = blockIdx.x;   // 0..255, one wave per WG
  const int l = threadIdx.x;  // 0..63
  const int c = l & 31;
  const int R = 2 * w + (l >> 5);  // my destination row
  uint64_t* fvb = (uint64_t*)(ws + WS_FV);
  uint16_t* bp = (uint16_t*)(ws + WS_BP);

  // transitions slice in registers: row R, cols c+32k
  float tr[16];
#pragma unroll
  for (int k = 0; k < 16; ++k) tr[k] = trans[(size_t)R * KK + c + 32 * k];

  const float* fb = feats + 63ll * TMAX * KK;  // batch 63
  const bool leader = (c == 0);
  float featNext = leader ? fb[R] : 0.0f;

  for (int t = 0; t < len; ++t) {
    uint64_t* slot = fvb + (size_t)(t & (DSLOT - 1)) * KK;
    // spin: lane l owns entries j = l + 64m; wave covers all 512
    uint64_t v[8];
    bool ok;
    do {
#pragma unroll
      for (int m = 0; m < 8; ++m)
        v[m] = __hip_atomic_load(&slot[l + 64 * m], __ATOMIC_RELAXED, __HIP_MEMORY_SCOPE_AGENT);
      ok = true;
#pragma unroll
      for (int m = 0; m < 8; ++m) ok = ok && ((int)(uint32_t)(v[m] >> 32) == t);
    } while (__any(!ok));
    float fvals[8];
#pragma unroll
    for (int m = 0; m < 8; ++m) fvals[m] = __uint_as_float((uint32_t)v[m]);

    const float featCur = featNext;
    if (leader && t + 1 < len) featNext = fb[(size_t)(t + 1) * KK + R];

    // cand j = c + 32k held by lane c+32(k&1), reg k>>1; ascending k = ascending j
    float bv;
    int bj;
#pragma unroll
    for (int k = 0; k < 16; ++k) {
      float fvk = __shfl(fvals[k >> 1], c + 32 * (k & 1));
      float cand = fvk + tr[k];
      if (k == 0) {
        bv = cand; bj = c;
      } else if (cand > bv) {
        bv = cand; bj = c + 32 * k;
      }
    }
    // reduce within 32-lane row group, first-index tie-break
#pragma unroll
    for (int m = 16; m >= 1; m >>= 1) {
      float ov = __shfl_xor(bv, m);
      int oj = __shfl_xor(bj, m);
      if (ov > bv || (ov == bv && oj < bj)) { bv = ov; bj = oj; }
    }
    if (leader) {
      const float vit = bv + featCur;
      const uint64_t pk = ((uint64_t)(uint32_t)(t + 1) << 32) | (uint64_t)__float_as_uint(vit);
      __hip_atomic_store(&fvb[(size_t)((t + 1) & (DSLOT - 1)) * KK + R], pk,
                         __ATOMIC_RELAXED, __HIP_MEMORY_SCOPE_AGENT);
      bp[(size_t)t * KK + R] = (uint16_t)bj;  // after fv store: off critical path
    }
  }

  if (w != 0) return;
  // terminal: score = max_j fv[j] + trans[STOP][j], best = first argmax
  {
    uint64_t* slot = fvb + (size_t)(len & (DSLOT - 1)) * KK;
    uint64_t v[8];
    bool ok;
    do {
#pragma unroll
      for (int m = 0; m < 8; ++m)
        v[m] = __hip_atomic_load(&slot[l + 64 * m], __ATOMIC_RELAXED, __HIP_MEMORY_SCOPE_AGENT);
      ok = true;
#pragma unroll
      for (int m = 0; m < 8; ++m) ok = ok && ((int)(uint32_t)(v[m] >> 32) == len);
    } while (__any(!ok));
    float tv;
    int tj;
#pragma unroll
    for (int m = 0; m < 8; ++m) {
      float x = __uint_as_float((uint32_t)v[m]) + trans[(size_t)STOPT * KK + l + 64 * m];
      if (m == 0) {
        tv = x; tj = l;
      } else if (x > tv) {
        tv = x; tj = l + 64 * m;
      }
    }
#pragma unroll
    for (int m = 32; m >= 1; m >>= 1) {
      float ov = __shfl_xor(tv, m);
      int oj = __shfl_xor(tj, m);
      if (ov > tv || (ov == tv && oj < tj)) { tv = ov; tj = oj; }
    }
    if (l == 0) {
      out[0] = tv;
      *((int*)(ws + WS_BEST)) = tj;
    }
  }
}

// speculative backtrack: per 16-step segment, walk all 512 possible entry tags
__global__ void __launch_bounds__(512) k_walk(const void* __restrict__ lens, char* ws) {
  const int len = read_len(lens);
  const uint16_t* bp = (const uint16_t*)(ws + WS_BP);
  uint16_t* E = (uint16_t*)(ws + WS_E);
  const int s = blockIdx.x;   // 64 segments
  const int k = threadIdx.x;  // 512 entry tags
  int tag = k;
  const int lo = s * 16;
  for (int t = lo + 15; t >= lo; --t)
    if (t < len) tag = bp[(size_t)t * KK + tag];
  E[s * KK + k] = (uint16_t)tag;
}

// compose segment maps from the top, then re-walk each segment and emit the path
__global__ void __launch_bounds__(64) k_emit(
    const void* __restrict__ lens, float* __restrict__ out, char* ws) {
  const int len = read_len(lens);
  const uint16_t* bp = (const uint16_t*)(ws + WS_BP);
  const uint16_t* E = (const uint16_t*)(ws + WS_E);
  __shared__ int entry[64];
  const int tid = threadIdx.x;
  if (tid == 0) {
    int st = *((const int*)(ws + WS_BEST));
    for (int s = 63; s >= 0; --s) { entry[s] = st; st = E[s * KK + st]; }
  }
  __syncthreads();
  {
    const int s = tid;
    int st = entry[s];
    for (int t = s * 16 + 15; t >= s * 16; --t) {
      if (t < len) {
        out[1 + t] = (float)st;
        st = bp[(size_t)t * KK + st];
      } else {
        out[1 + t] = -1.0f;
      }
    }
  }
}

extern "C" void kernel_launch(void* const* d_in, const int* in_sizes, int n_in,
                              void* d_out, int out_size, void* d_ws, size_t ws_size,
                              hipStream_t stream) {
  const float* feats = (const float*)d_in[0];
  const float* trans = (const float*)d_in[1];
  const void* lens = d_in[2];
  float* out = (float*)d_out;
  char* ws = (char*)d_ws;
  (void)in_sizes; (void)n_in; (void)out_size; (void)ws_size;

  k_init<<<1, 512, 0, stream>>>(ws);
  k_forward<<<256, 64, 0, stream>>>(feats, trans, lens, out, ws);
  k_walk<<<64, 512, 0, stream>>>(lens, ws);
  k_emit<<<1, 64, 0, stream>>>(lens, out, ws);
}